// Round 4
// baseline (52.383 us; speedup 1.0000x reference)
//
#include <hip/hip_runtime.h>
#include <math.h>

// ---------------------------------------------------------------------------
// CNN_88098369175791 — 8-WG distributed, 2 grid barriers (was 5).
// Each WG is self-sufficient up to the argmax gate (barrier 0) and up to its
// cm-MHA outputs (barrier 1). Redundant recompute (~3us VALU) is cheaper than
// cross-XCD barriers (~6us each). Weight-row-reuse: each 119-tap weight row
// is loaded once per 16-lane group and reused across 14-16 activations.
// ---------------------------------------------------------------------------

#define NWG 8
#define NT  1024

constexpr int WLEN = 140;
constexpr int TDN  = 14;
constexpr int NOFC = 119;

// ---------------- global arena (floats; at d_ws + 512 B) -------------------
constexpr int G_V16 = 0;     // [32]  vA|vB
constexpr int G_O   = 64;    // [4][119][16]

// ---------------- LDS arena (floats, per-WG, time-multiplexed) -------------
constexpr int EEG = 0;      // [16][119] live P0..LN
constexpr int WA  = 1904;   // 140
constexpr int WB  = 2044;   // 140
// P1 scratch (dead after v16):
constexpr int KPL = 2184;   // [14][119]
constexpr int VPL = 3850;   // [14][119]
constexpr int QPL = 5516;   // [4][119]
constexpr int SC  = 5992;   // [4][14]
constexpr int AVL = 6048;   // [4][119]
constexpr int WT4 = 6524;   // [4][119]
constexpr int MM  = 7000;   // [4][16] -> 7064
// P3 (over P1 scratch):
constexpr int PAT = 2184;   // [119][16]
constexpr int PBT = 4088;   // [119][16]
constexpr int LNT = 5992;   // [119][16] -> 7896
// cm arena:
constexpr int CKL = 7896;   // [119][20] (padded rows: bank-conflict dodge)
constexpr int CVL = 10276;  // [119][20]
constexpr int CQL = 12656;  // [60][16] -> 13616
// head (WG0, after gbar1; PAT dead):
constexpr int DD  = 2184;   // 238
constexpr int HH  = 2432;   // 119
constexpr int SMB = 13616;  // weight[16]; mi at +16
constexpr int ARENA = 13648; // 54,592 B

struct Args {
  const float *x, *td_in_w, *td_in_b, *td_out_w, *td_out_b;
  const float *cm_in_w, *cm_in_b, *cm_out_w, *cm_out_b;
  const float *mc_w, *mc_b, *max_fc_w, *max_fc_b, *proj_w;
  const float *ln_g, *ln_b, *fc_w, *fc_b;
  const float *out1_w, *out1_b, *out2_w, *out2_b;
  float *out;
  unsigned int *bar;   // d_ws (2 sites x 64B, memset to 0 per call)
  float *G;            // d_ws + 512
};

__device__ __forceinline__ float sigmf(float v) {
  return 1.0f / (1.0f + __expf(-v));
}

// device-scope grid barrier; relaxed poll + one trailing acquire fence.
__device__ __forceinline__ void gbar(unsigned int* p) {
  __syncthreads();
  if (threadIdx.x == 0) {
    __hip_atomic_fetch_add(p, 1u, __ATOMIC_ACQ_REL, __HIP_MEMORY_SCOPE_AGENT);
    while (__hip_atomic_load(p, __ATOMIC_RELAXED, __HIP_MEMORY_SCOPE_AGENT) < (unsigned)NWG) {
      __builtin_amdgcn_s_sleep(1);
    }
    __builtin_amdgcn_fence(__ATOMIC_ACQUIRE, "agent");
  }
  __syncthreads();
}

__global__ __launch_bounds__(NT) void fused_cnn_kernel(Args a) {
  __shared__ __align__(16) float S[ARENA];
  const int tid = threadIdx.x;
  const int wgid = blockIdx.x;
  const int grp = tid >> 4;        // 64 groups of 16
  const int lane16 = tid & 15;
  float* G = a.G;

  const int ab = wgid >> 2;          // td stream: WG 0-3 -> A, 4-7 -> B
  const int i0 = (wgid * 4) & 15;    // this WG's 4 q-rows / v16 slots

  // ---- P0: stage eeg_q, wavA, wavB ------------------------------------
  for (int t = tid; t < 16 * NOFC; t += NT) {
    int c = t / NOFC, tt = t - c * NOFC;
    S[EEG + t] = a.x[(1 + c) * WLEN + (WLEN - NOFC) + tt];
  }
  if (tid < WLEN) {
    S[WA + tid] = a.x[tid];
    S[WB + tid] = a.x[17 * WLEN + tid];
  }
  __syncthreads();

  // ---- P1: kp/vp (this ab, full) + qp (this WG's 4 rows) ---------------
  // weight-row-reuse: one 16-lane group owns one weight row, loops windows.
  {
    const float* xb = S + (ab ? WB : WA);
    for (int task = grp; task < 357; task += 64) {
      int typ = (task < 119) ? 0 : (task < 238) ? 1 : 2;  // kp, vp, qp
      int e = task - ((typ == 0) ? 0 : (typ == 1) ? 119 : 238);
      int row = ((typ == 0) ? NOFC : (typ == 1) ? 2 * NOFC : 0) + e;
      const float* wrow = a.td_in_w + row * NOFC;
      float w0 = wrow[lane16], w1 = wrow[lane16 + 16], w2 = wrow[lane16 + 32],
            w3 = wrow[lane16 + 48], w4 = wrow[lane16 + 64], w5 = wrow[lane16 + 80],
            w6 = wrow[lane16 + 96];
      float wt = (lane16 < 7) ? wrow[112 + lane16] : 0.0f;
      float b = a.td_in_b[row];
      if (typ < 2) {
        for (int j = 0; j < TDN; ++j) {
          const float* x = xb + j;
          float acc = w0 * x[lane16] + w1 * x[lane16 + 16] + w2 * x[lane16 + 32]
                    + w3 * x[lane16 + 48] + w4 * x[lane16 + 64] + w5 * x[lane16 + 80]
                    + w6 * x[lane16 + 96];
          if (lane16 < 7) acc += wt * x[112 + lane16];
#pragma unroll
          for (int m = 1; m < 16; m <<= 1) acc += __shfl_xor(acc, m);
          if (lane16 == 0) S[(typ ? VPL : KPL) + j * NOFC + e] = acc + b;
        }
      } else {
        for (int q = 0; q < 4; ++q) {
          const float* x = S + EEG + (i0 + q) * NOFC;
          float acc = w0 * x[lane16] + w1 * x[lane16 + 16] + w2 * x[lane16 + 32]
                    + w3 * x[lane16 + 48] + w4 * x[lane16 + 64] + w5 * x[lane16 + 80]
                    + w6 * x[lane16 + 96];
          if (lane16 < 7) acc += wt * x[112 + lane16];
#pragma unroll
          for (int m = 1; m < 16; m <<= 1) acc += __shfl_xor(acc, m);
          if (lane16 == 0) S[QPL + q * NOFC + e] = acc + b;
        }
      }
    }
  }
  __syncthreads();

  // ---- scores 4x14 ------------------------------------------------------
  if (grp < 56) {
    int q = grp / TDN, j = grp - q * TDN;
    const float* qr = S + QPL + q * NOFC;
    const float* kr = S + KPL + j * NOFC;
    float acc = 0.f;
#pragma unroll
    for (int t = 0; t < 7; ++t) acc += qr[lane16 + 16 * t] * kr[lane16 + 16 * t];
    if (lane16 < 7) acc += qr[112 + lane16] * kr[112 + lane16];
#pragma unroll
    for (int m = 1; m < 16; m <<= 1) acc += __shfl_xor(acc, m);
    if (lane16 == 0) S[SC + q * TDN + j] = acc * 0.09166984970282113f;
  }
  __syncthreads();

  // ---- softmax (4 rows) -------------------------------------------------
  if (tid < 4) {
    float* r = S + SC + tid * TDN;
    float m = r[0];
#pragma unroll
    for (int j = 1; j < TDN; ++j) m = fmaxf(m, r[j]);
    float sum = 0.f;
#pragma unroll
    for (int j = 0; j < TDN; ++j) { float p = __expf(r[j] - m); r[j] = p; sum += p; }
    float inv = 1.0f / sum;
#pragma unroll
    for (int j = 0; j < TDN; ++j) r[j] *= inv;
  }
  __syncthreads();

  // ---- av = attn @ vp : 4x119 ------------------------------------------
  for (int o = tid; o < 476; o += NT) {
    int q = o / NOFC, e = o - q * NOFC;
    float acc = 0.f;
#pragma unroll
    for (int j = 0; j < TDN; ++j) acc += S[SC + q * TDN + j] * S[VPL + j * NOFC + e];
    S[AVL + o] = acc;
  }
  __syncthreads();

  // ---- watt rows: 119 weight-reuse tasks, 4 dots each -------------------
  for (int e = grp; e < NOFC; e += 64) {
    const float* wrow = a.td_out_w + e * NOFC;
    float w0 = wrow[lane16], w1 = wrow[lane16 + 16], w2 = wrow[lane16 + 32],
          w3 = wrow[lane16 + 48], w4 = wrow[lane16 + 64], w5 = wrow[lane16 + 80],
          w6 = wrow[lane16 + 96];
    float wt = (lane16 < 7) ? wrow[112 + lane16] : 0.0f;
    float b = a.td_out_b[e];
    for (int q = 0; q < 4; ++q) {
      const float* x = S + AVL + q * NOFC;
      float acc = w0 * x[lane16] + w1 * x[lane16 + 16] + w2 * x[lane16 + 32]
                + w3 * x[lane16 + 48] + w4 * x[lane16 + 64] + w5 * x[lane16 + 80]
                + w6 * x[lane16 + 96];
      if (lane16 < 7) acc += wt * x[112 + lane16];
#pragma unroll
      for (int m = 1; m < 16; m <<= 1) acc += __shfl_xor(acc, m);
      if (lane16 == 0) S[WT4 + q * NOFC + e] = acc + b;
    }
  }
  __syncthreads();

  // ---- M[q][i] = eeg[i] . watt[q]  (exactly 64 dots) --------------------
  {
    int q = grp >> 4, i = grp & 15;
    const float* xr = S + EEG + i * NOFC;
    const float* wr = S + WT4 + q * NOFC;
    float acc = 0.f;
#pragma unroll
    for (int t = 0; t < 7; ++t) acc += xr[lane16 + 16 * t] * wr[lane16 + 16 * t];
    if (lane16 < 7) acc += xr[112 + lane16] * wr[112 + lane16];
#pragma unroll
    for (int m = 1; m < 16; m <<= 1) acc += __shfl_xor(acc, m);
    if (lane16 == 0) S[MM + q * 16 + i] = acc;
  }
  __syncthreads();

  // ---- v16 slots for this WG -> global ----------------------------------
  if (tid < 4) {
    float acc = a.mc_b[ab];
#pragma unroll
    for (int i = 0; i < 16; ++i) acc += a.mc_w[ab * 16 + i] * S[MM + tid * 16 + i];
    G[G_V16 + ab * 16 + i0 + tid] = fmaxf(acc, 0.f);
  }
  gbar(a.bar + 0);

  // ---- weight + argmax (replicated) -------------------------------------
  if (tid < 16) {
    float acc = a.max_fc_b[tid];
#pragma unroll
    for (int c = 0; c < 32; ++c) acc += a.max_fc_w[tid * 32 + c] * G[G_V16 + c];
    S[SMB + tid] = fmaxf(acc, 0.f);
  }
  __syncthreads();
  if (tid == 0) {
    float best = S[SMB]; int mi = 0;
    for (int r = 1; r < 16; ++r) {
      float w = S[SMB + r];
      if (w > best) { best = w; mi = r; }
    }
    if (mi > TDN - 1) mi = TDN - 1;   // jnp.take clamps OOB
    S[SMB + 16] = (float)mi;
  }
  __syncthreads();

  // ---- P3 (replicated): PAT/PBT/LNT in [t][16] --------------------------
  {
    const int mi = (int)S[SMB + 16];
    for (int o = tid; o < 3808; o += NT) {
      int abp = o / 1904, r2 = o - abp * 1904;
      int t = r2 >> 4, c = r2 & 15;
      S[(abp ? PBT : PAT) + r2] = a.proj_w[abp * 16 + c] * S[(abp ? WB : WA) + t + mi];
    }
    if (tid < NOFC) {
      float xv[16];
      float mu = 0.f;
#pragma unroll
      for (int c = 0; c < 16; ++c) { xv[c] = S[EEG + c * NOFC + tid]; mu += xv[c]; }
      mu *= (1.0f / 16.0f);
      float var = 0.f;
#pragma unroll
      for (int c = 0; c < 16; ++c) { float d = xv[c] - mu; var += d * d; }
      var *= (1.0f / 16.0f);
      float inv = 1.0f / sqrtf(var + 1e-5f);
#pragma unroll
      for (int c = 0; c < 16; ++c)
        S[LNT + tid * 16 + c] = (xv[c] - mu) * inv * a.ln_g[c] + a.ln_b[c];
    }
  }
  __syncthreads();

  // ---- cm qkv (self-sufficient): K,V full + Q rows for this WG ----------
  const int m = wgid >> 1;
  const int r0 = (wgid & 1) ? 60 : 0;
  const int nr = (wgid & 1) ? 59 : 60;
  {
    const int dsrc = (m == 0) ? PAT : (m == 3) ? PBT : LNT;
    const int ksrc = (m == 1) ? PAT : (m == 2) ? PBT : LNT;
    const int nout = 3808 + nr * 16;
    for (int o = tid; o < nout; o += NT) {
      int which, t, e, src, dst;
      if (o < 1904)      { which = 1; t = o >> 4;          e = o & 15; src = ksrc; dst = CKL + t * 20 + e; }
      else if (o < 3808) { int r1 = o - 1904; which = 2; t = r1 >> 4; e = r1 & 15; src = ksrc; dst = CVL + t * 20 + e; }
      else               { int r1 = o - 3808; which = 0; t = r0 + (r1 >> 4); e = r1 & 15; src = dsrc; dst = CQL + (r1 >> 4) * 16 + e; }
      const float4* sa = (const float4*)(S + src + t * 16);
      const float4* wr = (const float4*)(a.cm_in_w + (m * 48 + which * 16 + e) * 16);
      float4 s0 = sa[0], s1 = sa[1], s2 = sa[2], s3 = sa[3];
      float4 q0 = wr[0], q1 = wr[1], q2 = wr[2], q3 = wr[3];
      float d0 = s0.x * q0.x + s0.y * q0.y + s0.z * q0.z + s0.w * q0.w;
      float d1 = s1.x * q1.x + s1.y * q1.y + s1.z * q1.z + s1.w * q1.w;
      float d2 = s2.x * q2.x + s2.y * q2.y + s2.z * q2.z + s2.w * q2.w;
      float d3 = s3.x * q3.x + s3.y * q3.y + s3.z * q3.z + s3.w * q3.w;
      S[dst] = a.cm_in_b[m * 48 + which * 16 + e] + ((d0 + d1) + (d2 + d3));
    }
  }
  __syncthreads();

  // ---- cm attention: one row per 16-lane group --------------------------
  if (grp < nr) {
    const int r = r0 + grp;
    float qv[16];
    {
      const float* qg = S + CQL + grp * 16;
#pragma unroll
      for (int e = 0; e < 16; ++e) qv[e] = qg[e];
    }
    float p[8];
    float mx = -1e30f;
#pragma unroll
    for (int cc = 0; cc < 8; ++cc) {
      int u = lane16 + cc * 16;
      int uc = (u < NOFC) ? u : 0;
      const float4* k4 = (const float4*)(S + CKL + uc * 20);
      float4 k0 = k4[0], k1 = k4[1], k2 = k4[2], k3 = k4[3];
      float d0 = qv[0]*k0.x + qv[1]*k0.y + qv[2]*k0.z + qv[3]*k0.w;
      float d1 = qv[4]*k1.x + qv[5]*k1.y + qv[6]*k1.z + qv[7]*k1.w;
      float d2 = qv[8]*k2.x + qv[9]*k2.y + qv[10]*k2.z + qv[11]*k2.w;
      float d3 = qv[12]*k3.x + qv[13]*k3.y + qv[14]*k3.z + qv[15]*k3.w;
      float sc = ((d0 + d1) + (d2 + d3)) * 0.25f;
      p[cc] = (u < NOFC) ? sc : -1e30f;
      mx = fmaxf(mx, p[cc]);
    }
#pragma unroll
    for (int d = 1; d < 16; d <<= 1) mx = fmaxf(mx, __shfl_xor(mx, d));
    float sum = 0.f;
#pragma unroll
    for (int cc = 0; cc < 8; ++cc) { p[cc] = __expf(p[cc] - mx); sum += p[cc]; }
#pragma unroll
    for (int d = 1; d < 16; d <<= 1) sum += __shfl_xor(sum, d);
    float inv = 1.0f / sum;

    float oa[16];
#pragma unroll
    for (int e = 0; e < 16; ++e) oa[e] = 0.f;
#pragma unroll
    for (int cc = 0; cc < 8; ++cc) {
      int u = lane16 + cc * 16;
      if (u < NOFC) {
        const float4* v4 = (const float4*)(S + CVL + u * 20);
        float4 v0 = v4[0], v1 = v4[1], v2 = v4[2], v3 = v4[3];
        float pv = p[cc];
        oa[0] += pv*v0.x; oa[1] += pv*v0.y; oa[2] += pv*v0.z; oa[3] += pv*v0.w;
        oa[4] += pv*v1.x; oa[5] += pv*v1.y; oa[6] += pv*v1.z; oa[7] += pv*v1.w;
        oa[8] += pv*v2.x; oa[9] += pv*v2.y; oa[10] += pv*v2.z; oa[11] += pv*v2.w;
        oa[12] += pv*v3.x; oa[13] += pv*v3.y; oa[14] += pv*v3.z; oa[15] += pv*v3.w;
      }
    }
#pragma unroll
    for (int e = 0; e < 16; ++e) {
#pragma unroll
      for (int d = 1; d < 16; d <<= 1) oa[e] += __shfl_xor(oa[e], d);
      oa[e] *= inv;
    }
    {
      const float* ow = a.cm_out_w + m * 256 + lane16 * 16;
      float acc = a.cm_out_b[m * 16 + lane16];
#pragma unroll
      for (int e = 0; e < 16; ++e) acc += oa[e] * ow[e];
      G[G_O + (m * NOFC + r) * 16 + lane16] = acc;
    }
  }
  gbar(a.bar + 16);

  // ---- head (WG0 only) ---------------------------------------------------
  if (wgid == 0) {
    for (int o = tid; o < 2 * NOFC; o += NT) {
      int half = o / NOFC, t = o - half * NOFC;
      const float* A = G + G_O + ((half ? 3 : 0) * NOFC + t) * 16;
      const float* B = G + G_O + ((half ? 2 : 1) * NOFC + t) * 16;
      float acc = 0.f;
#pragma unroll
      for (int c = 0; c < 16; ++c) acc += A[c] * B[c];
      S[DD + o] = sigmf(a.fc_w[half] * acc + a.fc_b[half]);
    }
    __syncthreads();
    for (int o = grp; o < NOFC; o += 64) {       // out1: 238-dot
      const float* wrow = a.out1_w + o * 238;
      float a0 = 0.f, a1 = 0.f;
#pragma unroll
      for (int t = 0; t < 14; ++t) {
        float wv = wrow[lane16 + 16 * t];
        float xv = S[DD + lane16 + 16 * t];
        if (t & 1) a1 += wv * xv; else a0 += wv * xv;
      }
      if (lane16 < 14) a0 += wrow[224 + lane16] * S[DD + 224 + lane16];
      float acc = a0 + a1;
#pragma unroll
      for (int m = 1; m < 16; m <<= 1) acc += __shfl_xor(acc, m);
      if (lane16 == 0) S[HH + o] = sigmf(acc + a.out1_b[o]);
    }
    __syncthreads();
    if (tid < 32) {
      int o2 = tid >> 4;
      const float* wrow = a.out2_w + o2 * NOFC;
      float a0 = 0.f;
#pragma unroll
      for (int t = 0; t < 8; ++t) {
        int idx = lane16 + 16 * t;
        if (idx < NOFC) a0 += wrow[idx] * S[HH + idx];
      }
      float acc = a0;
#pragma unroll
      for (int m = 1; m < 16; m <<= 1) acc += __shfl_xor(acc, m);
      if (lane16 == 0) a.out[o2] = sigmf(acc + a.out2_b[o2]);
    }
  }
}

extern "C" void kernel_launch(void* const* d_in, const int* in_sizes, int n_in,
                              void* d_out, int out_size, void* d_ws, size_t ws_size,
                              hipStream_t stream) {
  Args a;
  a.x        = (const float*)d_in[0];
  a.td_in_w  = (const float*)d_in[1];
  a.td_in_b  = (const float*)d_in[2];
  a.td_out_w = (const float*)d_in[3];
  a.td_out_b = (const float*)d_in[4];
  a.cm_in_w  = (const float*)d_in[5];
  a.cm_in_b  = (const float*)d_in[6];
  a.cm_out_w = (const float*)d_in[7];
  a.cm_out_b = (const float*)d_in[8];
  a.mc_w     = (const float*)d_in[9];
  a.mc_b     = (const float*)d_in[10];
  a.max_fc_w = (const float*)d_in[11];
  a.max_fc_b = (const float*)d_in[12];
  a.proj_w   = (const float*)d_in[13];
  a.ln_g     = (const float*)d_in[14];
  a.ln_b     = (const float*)d_in[15];
  a.fc_w     = (const float*)d_in[16];
  a.fc_b     = (const float*)d_in[17];
  a.out1_w   = (const float*)d_in[18];
  a.out1_b   = (const float*)d_in[19];
  a.out2_w   = (const float*)d_in[20];
  a.out2_b   = (const float*)d_in[21];
  a.out      = (float*)d_out;
  a.bar      = (unsigned int*)d_ws;
  a.G        = (float*)((char*)d_ws + 512);

  // zero the 2 barrier counters (64 B apart) every call — graph replays this.
  hipMemsetAsync(d_ws, 0, 512, stream);
  fused_cnn_kernel<<<dim3(NWG), dim3(NT), 0, stream>>>(a);
}